// Round 7
// baseline (86.912 us; speedup 1.0000x reference)
//
#include <hip/hip_runtime.h>
#include <hip/hip_bf16.h>
#include <stdint.h>

// MultiHeadAttention pipeline for MI355X (gfx950), all-MFMA bf16.
// Reference's "softmax" divides e[s,t] by D[t] (row-sum of row t), so the
// denominator is per-KEY and folds into V: out[d,i] = sum_j e[i,j] * v'[d,j],
// v'[d,j] = v[d,j]/D[j].
// Round 7: waves own 32 q-rows (2 MFMA fragment sets) so each K/V LDS frag
// read feeds 2 MFMAs (LDS-read pipe was the bottleneck); denom folds rD into
// a separate V' buffer (attn epilogue = exp2 only); dead/masked sub-tile
// skipping on the diagonal. Staging skeleton identical to round 5/6
// (16B-multiple LDS row strides, double-barrier + reg prefetch, heavy-first).
#define NB 4
#define NH 16
#define HDIM 64
#define NS 1024
#define NE 1024

typedef __bf16 bf16x8 __attribute__((ext_vector_type(8)));
typedef __bf16 bf16x2_t __attribute__((ext_vector_type(2)));
typedef float f32x4 __attribute__((ext_vector_type(4)));
typedef unsigned int uint4v __attribute__((ext_vector_type(4)));
typedef unsigned int uint2v __attribute__((ext_vector_type(2)));
typedef unsigned short u16;

#if defined(__has_builtin)
#if __has_builtin(__builtin_amdgcn_global_load_lds)
#define HAVE_GLDS 1
#endif
#endif

__device__ __forceinline__ u16 f2bf(float f) {
  return __builtin_bit_cast(u16, (__bf16)f);   // RNE
}
__device__ __forceinline__ unsigned pk2(float a, float b) {
  bf16x2_t v; v[0] = (__bf16)a; v[1] = (__bf16)b;
  return __builtin_bit_cast(unsigned, v);      // v_cvt_pk_bf16_f32
}
__device__ __forceinline__ float fexp2(float x) {
#if defined(__has_builtin)
#if __has_builtin(__builtin_amdgcn_exp2f)
  return __builtin_amdgcn_exp2f(x);
#else
  return __expf(x * 0.69314718056f);
#endif
#else
  return __expf(x * 0.69314718056f);
#endif
}
__device__ __forceinline__ f32x4 mfma16(bf16x8 a, bf16x8 b, f32x4 c) {
  return __builtin_amdgcn_mfma_f32_16x16x32_bf16(a, b, c, 0, 0, 0);
}
__device__ __forceinline__ bf16x8 ld_bf8(const u16* p) {
  return __builtin_bit_cast(bf16x8, *(const uint4v*)p);
}
#ifdef HAVE_GLDS
__device__ __forceinline__ void gld16(const void* g, void* l) {
  __builtin_amdgcn_global_load_lds(
      (__attribute__((address_space(1))) void*)g,
      (__attribute__((address_space(3))) void*)l, 16, 0, 0);
}
#endif

// ---------------------------------------------------------------------------
// Kernel 1: per-head projections q/k/v (z=0..2) + Wf fp32->bf16 (z=3).
// Wq pre-scaled by log2e/8 (log2-domain scores). qT/kT: [bh][s][d]; v: [bh][d][s].
__global__ __launch_bounds__(256) void proj_kernel(
    const float* __restrict__ q_in, const float* __restrict__ k_in,
    const float* __restrict__ v_in, const float* __restrict__ Wq,
    const float* __restrict__ Wk, const float* __restrict__ Wv,
    const float* __restrict__ Wf,
    u16* __restrict__ qT, u16* __restrict__ kT, u16* __restrict__ vv,
    u16* __restrict__ Wf16)
{
  const int which = blockIdx.z;
  const int tid = threadIdx.x;

  if (which == 3) {  // Wf conversion
    int chunk = blockIdx.y * 4 + blockIdx.x;
    #pragma unroll
    for (int jj = 0; jj < 4; ++jj) {
      int i = chunk * 1024 + tid + 256 * jj;
      float4 f = ((const float4*)Wf)[i];
      uint2v p;
      p[0] = pk2(f.x, f.y);
      p[1] = pk2(f.z, f.w);
      ((uint2v*)Wf16)[i] = p;
    }
    return;
  }

  const int bh = blockIdx.y;
  const int b = bh >> 4, h = bh & 15;
  const int s0 = blockIdx.x * 256;
  const int w = tid >> 6, l = tid & 63, lr = l & 15, lg = l >> 4;

  const float* x = (which == 0) ? q_in : (which == 1) ? k_in : v_in;
  const float* W = ((which == 0) ? Wq : (which == 1) ? Wk : Wv) + h * 4096;
  const float wsc = (which == 0) ? 0.18033688f : 1.0f;  // (1/8)*log2(e)

  __shared__ alignas(16) u16 xT[256][72];
  __shared__ alignas(16) u16 Wl[64][72];

  #pragma unroll
  for (int j = 0; j < 4; ++j) {
    int i = tid * 4 + j;
    int d = i >> 4;
    int e0 = (i & 15) * 4;
    float4 f = *(const float4*)(W + d * 64 + e0);
    uint2v p;
    p[0] = pk2(f.x * wsc, f.y * wsc);
    p[1] = pk2(f.z * wsc, f.w * wsc);
    *(uint2v*)&Wl[d][e0] = p;
  }
  {
    const float* xp = x + ((size_t)b * NE + h * 64) * NS + s0 + tid;
    #pragma unroll
    for (int j = 0; j < 8; ++j) {
      uint4v pk;
      #pragma unroll
      for (int q = 0; q < 4; ++q) {
        float f0 = xp[(size_t)(j * 8 + q * 2) * NS];
        float f1 = xp[(size_t)(j * 8 + q * 2 + 1) * NS];
        pk[q] = pk2(f0, f1);
      }
      *(uint4v*)&xT[tid][j * 8] = pk;
    }
  }
  __syncthreads();

  bf16x8 af[4][2];
  #pragma unroll
  for (int mt = 0; mt < 4; ++mt) {
    af[mt][0] = ld_bf8(&Wl[mt * 16 + lr][lg * 8]);
    af[mt][1] = ld_bf8(&Wl[mt * 16 + lr][32 + lg * 8]);
  }
  f32x4 acc[4][4] = {};
  #pragma unroll
  for (int nt = 0; nt < 4; ++nt) {
    bf16x8 b0 = ld_bf8(&xT[w * 64 + nt * 16 + lr][lg * 8]);
    bf16x8 b1 = ld_bf8(&xT[w * 64 + nt * 16 + lr][32 + lg * 8]);
    #pragma unroll
    for (int mt = 0; mt < 4; ++mt) {
      acc[mt][nt] = mfma16(af[mt][0], b0, acc[mt][nt]);
      acc[mt][nt] = mfma16(af[mt][1], b1, acc[mt][nt]);
    }
  }

  if (which < 2) {
    u16* o = ((which == 0) ? qT : kT) + (size_t)bh * NS * 64;
    #pragma unroll
    for (int mt = 0; mt < 4; ++mt)
      #pragma unroll
      for (int nt = 0; nt < 4; ++nt) {
        int s = s0 + w * 64 + nt * 16 + lr;
        int d = mt * 16 + lg * 4;
        uint2v p;
        p[0] = pk2(acc[mt][nt][0], acc[mt][nt][1]);
        p[1] = pk2(acc[mt][nt][2], acc[mt][nt][3]);
        *(uint2v*)(o + (size_t)s * 64 + d) = p;
      }
  } else {
    u16* o = vv + (size_t)bh * 64 * NS;
    #pragma unroll
    for (int mt = 0; mt < 4; ++mt)
      #pragma unroll
      for (int nt = 0; nt < 4; ++nt)
        #pragma unroll
        for (int jr = 0; jr < 4; ++jr) {
          int d = mt * 16 + lg * 4 + jr;
          int s = s0 + w * 64 + nt * 16 + lr;
          o[(size_t)d * NS + s] = f2bf(acc[mt][nt][jr]);
        }
  }
}

// ---------------------------------------------------------------------------
// Kernel 2: denom + V'-fold. 256 thr / 4 waves; each wave owns 32 q-rows
// (2 fragment sets) so K-frag reads feed 2 MFMAs. Swapped QK (A=K m=key,
// B=Q n=query), log2 domain. Writes vvs[d][j] = vv[d][j] * (1/D[j]) for this
// block's 128 columns. grid 512, heavy-first.
__global__ __launch_bounds__(256) void denom_kernel(
    const u16* __restrict__ qT, const u16* __restrict__ kT,
    const u16* __restrict__ vv, u16* __restrict__ vvs)
{
  const int wg = blockIdx.x;
  const int rt = 7 - (wg >> 6);
  const int bh = wg & 63;
  const int i0 = rt * 128;
  const int tid = threadIdx.x, w = tid >> 6, l = tid & 63, lr = l & 15, lg = l >> 4;
  __shared__ alignas(16) u16 klds[128][72];
  __shared__ alignas(16) float Dsh[128];
  const u16* qb = qT + (size_t)bh * NS * 64;
  const u16* kb = kT + (size_t)bh * NS * 64;
  const int r0 = i0 + w * 32;
  int gi[2];
  bf16x8 bq[2][2];
  #pragma unroll
  for (int s = 0; s < 2; ++s) {
    gi[s] = r0 + s * 16 + lr;
    bq[s][0] = ld_bf8(qb + (size_t)gi[s] * 64 + lg * 8);
    bq[s][1] = ld_bf8(qb + (size_t)gi[s] * 64 + 32 + lg * 8);
  }
  float den[2] = {0.f, 0.f};
  const int nkt = rt + 1;
  uint4v kreg[4];
  const int krow = tid >> 3, kcx = tid & 7;   // rows 0..31 (+32j)
  #pragma unroll
  for (int j = 0; j < 4; ++j)
    kreg[j] = *(const uint4v*)(kb + (size_t)(krow + j * 32) * 64 + kcx * 8);
  for (int t = 0; t < nkt; ++t) {
    __syncthreads();
    #pragma unroll
    for (int j = 0; j < 4; ++j)
      *(uint4v*)&klds[krow + j * 32][kcx * 8] = kreg[j];
    __syncthreads();
    const int t0 = t * 128;
    if (t + 1 < nkt) {
      #pragma unroll
      for (int j = 0; j < 4; ++j)
        kreg[j] = *(const uint4v*)(kb + (size_t)(t0 + 128 + krow + j * 32) * 64 + kcx * 8);
    }
    #pragma unroll
    for (int hh = 0; hh < 2; ++hh) {
      const int t0h = t0 + hh * 64;
      bool dead0 = t0h > r0 + 15, dead1 = t0h > r0 + 31;
      bool msk0 = !dead0 && (t0h + 63 > r0), msk1 = !dead1 && (t0h + 63 > r0 + 16);
      if (dead0 && dead1) continue;
      #pragma unroll
      for (int mt = 0; mt < 4; ++mt) {
        bf16x8 a0 = ld_bf8(&klds[hh * 64 + mt * 16 + lr][lg * 8]);
        bf16x8 a1 = ld_bf8(&klds[hh * 64 + mt * 16 + lr][32 + lg * 8]);
        #pragma unroll
        for (int s = 0; s < 2; ++s) {
          bool dead = s ? dead1 : dead0, msk = s ? msk1 : msk0;
          if (dead) continue;
          f32x4 z = {0.f, 0.f, 0.f, 0.f};
          f32x4 sc = mfma16(a0, bq[s][0], z);
          sc = mfma16(a1, bq[s][1], sc);
          if (!msk) {
            den[s] += fexp2(sc[0]) + fexp2(sc[1]) + fexp2(sc[2]) + fexp2(sc[3]);
          } else {
            #pragma unroll
            for (int r = 0; r < 4; ++r) {
              int gt = t0h + mt * 16 + lg * 4 + r;
              den[s] += (gt <= gi[s]) ? fexp2(sc[r]) : 0.f;
            }
          }
        }
      }
    }
  }
  #pragma unroll
  for (int s = 0; s < 2; ++s) {
    float d = den[s];
    d += __shfl_xor(d, 16);
    d += __shfl_xor(d, 32);
    if (l < 16) Dsh[w * 32 + s * 16 + lr] = 1.0f / d;
  }
  __syncthreads();
  // V' fold: vvs[d][i0+c] = vv[d][i0+c] * rD[i0+c], 64 rows x 128 cols
  const u16* vi = vv + (size_t)bh * 64 * NS + i0;
  u16* vo = vvs + (size_t)bh * 64 * NS + i0;
  const int c = (tid & 15) * 8;
  #pragma unroll
  for (int p4 = 0; p4 < 4; ++p4) {
    int d = p4 * 16 + (tid >> 4);
    bf16x8 vx = ld_bf8(vi + (size_t)d * NS + c);
    float r[8];
    #pragma unroll
    for (int i = 0; i < 8; ++i) r[i] = (float)vx[i] * Dsh[c + i];
    uint4v o;
    o[0] = pk2(r[0], r[1]); o[1] = pk2(r[2], r[3]);
    o[2] = pk2(r[4], r[5]); o[3] = pk2(r[6], r[7]);
    *(uint4v*)(vo + (size_t)d * NS + c) = o;
  }
}

// ---------------------------------------------------------------------------
// Kernel 3: attention. 256 thr / 4 waves; wave owns 32 q-rows (2 sets), so
// K/V frag reads feed 2 MFMAs. P = exp2(sc) (denominator folded in V').
// Dead/masked diagonal sub-tile skipping. grid 512, heavy-first.
__global__ __launch_bounds__(256) void attn_kernel(
    const u16* __restrict__ qT, const u16* __restrict__ kT,
    const u16* __restrict__ vvs, u16* __restrict__ X)
{
  const int wg = blockIdx.x;
  const int rt = 7 - (wg >> 6);
  const int bh = wg & 63;
  const int b = bh >> 4, h = bh & 15;
  const int i0 = rt * 128;
  const int tid = threadIdx.x, w = tid >> 6, l = tid & 63, lr = l & 15, lg = l >> 4;
  __shared__ alignas(16) u16 klds[128][72];     // [key][d]
  __shared__ alignas(16) u16 vlds[64][136];     // [d][j]
  __shared__ alignas(16) u16 plds[4][32][72];   // per-wave [q-row][key]
  const u16* qb = qT + (size_t)bh * NS * 64;
  const u16* kb = kT + (size_t)bh * NS * 64;
  const u16* vb = vvs + (size_t)bh * 64 * NS;
  const int r0 = i0 + w * 32;
  int gi[2];
  bf16x8 bq[2][2];
  #pragma unroll
  for (int s = 0; s < 2; ++s) {
    gi[s] = r0 + s * 16 + lr;
    bq[s][0] = ld_bf8(qb + (size_t)gi[s] * 64 + lg * 8);
    bq[s][1] = ld_bf8(qb + (size_t)gi[s] * 64 + 32 + lg * 8);
  }
  f32x4 acc[2][4] = {};
  const int nkt = rt + 1;
  uint4v kreg[4], vreg[4];
  const int krow = tid >> 3, kcx = tid & 7;    // K rows 0..31 (+32j)
  const int vrow = tid >> 4, vcx = tid & 15;   // V rows 0..15 (+16j)
  #pragma unroll
  for (int j = 0; j < 4; ++j) {
    kreg[j] = *(const uint4v*)(kb + (size_t)(krow + j * 32) * 64 + kcx * 8);
    vreg[j] = *(const uint4v*)(vb + (size_t)(vrow + j * 16) * NS + vcx * 8);
  }
  for (int t = 0; t < nkt; ++t) {
    __syncthreads();
    #pragma unroll
    for (int j = 0; j < 4; ++j) {
      *(uint4v*)&klds[krow + j * 32][kcx * 8] = kreg[j];
      *(uint4v*)&vlds[vrow + j * 16][vcx * 8] = vreg[j];
    }
    __syncthreads();
    const int t0 = t * 128;
    if (t + 1 < nkt) {
      const int t0n = t0 + 128;
      #pragma unroll
      for (int j = 0; j < 4; ++j) {
        kreg[j] = *(const uint4v*)(kb + (size_t)(t0n + krow + j * 32) * 64 + kcx * 8);
        vreg[j] = *(const uint4v*)(vb + (size_t)(vrow + j * 16) * NS + t0n + vcx * 8);
      }
    }
    #pragma unroll
    for (int hh = 0; hh < 2; ++hh) {
      const int t0h = t0 + hh * 64;
      bool dead0 = t0h > r0 + 15, dead1 = t0h > r0 + 31;
      bool msk0 = !dead0 && (t0h + 63 > r0), msk1 = !dead1 && (t0h + 63 > r0 + 16);
      if (dead0 && dead1) continue;
      // QK^T: A=K (m=key), B=Q (n=query); exp2 -> plds (two q-sets per frag)
      #pragma unroll
      for (int mt = 0; mt < 4; ++mt) {
        bf16x8 a0 = ld_bf8(&klds[hh * 64 + mt * 16 + lr][lg * 8]);
        bf16x8 a1 = ld_bf8(&klds[hh * 64 + mt * 16 + lr][32 + lg * 8]);
        #pragma unroll
        for (int s = 0; s < 2; ++s) {
          bool dead = s ? dead1 : dead0, msk = s ? msk1 : msk0;
          if (dead) continue;
          f32x4 z = {0.f, 0.f, 0.f, 0.f};
          f32x4 sc = mfma16(a0, bq[s][0], z);
          sc = mfma16(a1, bq[s][1], sc);
          uint2v p;
          if (!msk) {
            p[0] = pk2(fexp2(sc[0]), fexp2(sc[1]));
            p[1] = pk2(fexp2(sc[2]), fexp2(sc[3]));
          } else {
            int g0 = t0h + mt * 16 + lg * 4;
            float e0 = (g0 + 0 <= gi[s]) ? fexp2(sc[0]) : 0.f;
            float e1 = (g0 + 1 <= gi[s]) ? fexp2(sc[1]) : 0.f;
            float e2 = (g0 + 2 <= gi[s]) ? fexp2(sc[2]) : 0.f;
            float e3 = (g0 + 3 <= gi[s]) ? fexp2(sc[3]) : 0.f;
            p[0] = pk2(e0, e1);
            p[1] = pk2(e2, e3);
          }
          *(uint2v*)&plds[w][s * 16 + lr][mt * 16 + lg * 4] = p;
        }
      }
      // PV: A = P (m=query, k=j), B = v' (k=j, n=d); V frags shared by sets
      bf16x8 ap[2][2];
      #pragma unroll
      for (int s = 0; s < 2; ++s) {
        bool dead = s ? dead1 : dead0;
        if (!dead) {
          ap[s][0] = ld_bf8(&plds[w][s * 16 + lr][lg * 8]);
          ap[s][1] = ld_bf8(&plds[w][s * 16 + lr][32 + lg * 8]);
        }
      }
      __builtin_amdgcn_s_setprio(1);
      #pragma unroll
      for (int nt = 0; nt < 4; ++nt) {
        bf16x8 v0 = ld_bf8(&vlds[nt * 16 + lr][hh * 64 + lg * 8]);
        bf16x8 v1 = ld_bf8(&vlds[nt * 16 + lr][hh * 64 + 32 + lg * 8]);
        #pragma unroll
        for (int s = 0; s < 2; ++s) {
          bool dead = s ? dead1 : dead0;
          if (dead) continue;
          acc[s][nt] = mfma16(ap[s][0], v0, acc[s][nt]);
          acc[s][nt] = mfma16(ap[s][1], v1, acc[s][nt]);
        }
      }
      __builtin_amdgcn_s_setprio(0);
    }
  }
  u16* Xp = X + (size_t)b * NS * NE + h * 64;
  #pragma unroll
  for (int s = 0; s < 2; ++s)
    #pragma unroll
    for (int nt = 0; nt < 4; ++nt)
      #pragma unroll
      for (int jr = 0; jr < 4; ++jr) {
        int srow = r0 + s * 16 + lg * 4 + jr;
        Xp[(size_t)srow * NE + nt * 16 + lr] = f2bf(acc[s][nt][jr]);
      }
}

// ---------------------------------------------------------------------------
// Kernel 4: out[b][e][s] = sum_f Wf[e][f] * X[b][s][f]. 128x128 tile, 4 waves
// (each 64x64), BK=64, global_load_lds into double-buffered XOR-swizzled LDS.
__global__ __launch_bounds__(256) void final_gemm(
    const u16* __restrict__ Wf16, const u16* __restrict__ X,
    float* __restrict__ out)
{
  const int b = blockIdx.z;
  const int e0 = blockIdx.y * 128;
  const int s0 = blockIdx.x * 128;
  const int tid = threadIdx.x, w = tid >> 6, l = tid & 63, lr = l & 15, lg = l >> 4;
  const int wm = (w >> 1) * 64, wn = (w & 1) * 64;
  __shared__ alignas(16) u16 Ald[2][128][64];
  __shared__ alignas(16) u16 Bld[2][128][64];
  const u16* Xb = X + (size_t)b * NS * NE;
  f32x4 acc[4][4] = {};

  // chunk c = tid + 256j: row = c>>3, byte col (c&7)*16, XOR-swizzled source
  #define FG_ISSUE(p, k0)                                                     \
    {                                                                         \
      _Pragma("unroll")                                                       \
      for (int j = 0; j < 4; ++j) {                                           \
        int c = tid + 256 * j;                                                \
        int r = c >> 3;                                                       \
        int sc_ = ((c & 7) * 16) ^ ((r & 7) << 4);                            \
        const char* ga = (const char*)(Wf16 + (size_t)(e0 + r) * NE + (k0)) + sc_; \
        const char* gb = (const char*)(Xb + (size_t)(s0 + r) * NE + (k0)) + sc_;   \
        char* la = (char*)&Ald[p][0][0] + c * 16;                             \
        char* lb = (char*)&Bld[p][0][0] + c * 16;                             \
        STAGE16(ga, la);                                                      \
        STAGE16(gb, lb);                                                      \
      }                                                                       \
    }
#ifdef HAVE_GLDS
  #define STAGE16(g, l_) gld16((g), (l_))
#else
  #define STAGE16(g, l_) (*(uint4v*)(l_) = *(const uint4v*)(g))
#endif

  FG_ISSUE(0, 0);
  __syncthreads();
  for (int t = 0; t < 16; ++t) {
    const int p = t & 1;
    if (t < 15) FG_ISSUE(p ^ 1, (t + 1) * 64);
    __builtin_amdgcn_s_setprio(1);
    #pragma unroll
    for (int kk = 0; kk < 2; ++kk) {
      bf16x8 a[4], bb[4];
      #pragma unroll
      for (int mt = 0; mt < 4; ++mt) {
        int R = wm + mt * 16 + lr;
        a[mt] = ld_bf8((const u16*)((const char*)&Ald[p][R][0] +
                                    ((kk * 64 + lg * 16) ^ ((R & 7) << 4))));
      }
      #pragma unroll
      for (int nt = 0; nt < 4; ++nt) {
        int R = wn + nt * 16 + lr;
        bb[nt] = ld_bf8((const u16*)((const char*)&Bld[p][R][0] +
                                     ((kk * 64 + lg * 16) ^ ((R & 7) << 4))));
      }
      #pragma unroll
      for (int mt = 0; mt < 4; ++mt)
        #pragma unroll
        for (int nt = 0; nt < 4; ++nt)
          acc[mt][nt] = mfma16(a[mt], bb[nt], acc[mt][nt]);
    }
    __builtin_amdgcn_s_setprio(0);
    __syncthreads();
  }
  #pragma unroll
  for (int mt = 0; mt < 4; ++mt)
    #pragma unroll
    for (int nt = 0; nt < 4; ++nt) {
      int e = e0 + wm + mt * 16 + lg * 4;
      int s = s0 + wn + nt * 16 + lr;
      float* op = out + ((size_t)b * NE + e) * NS + s;
      op[0] = acc[mt][nt][0];
      op[NS] = acc[mt][nt][1];
      op[2 * NS] = acc[mt][nt][2];
      op[3 * NS] = acc[mt][nt][3];
    }
}

// ---------------------------------------------------------------------------
extern "C" void kernel_launch(void* const* d_in, const int* in_sizes, int n_in,
                              void* d_out, int out_size, void* d_ws, size_t ws_size,
                              hipStream_t stream) {
  (void)in_sizes; (void)n_in; (void)out_size; (void)ws_size;
  const float* q_in = (const float*)d_in[0];
  const float* k_in = (const float*)d_in[1];
  const float* v_in = (const float*)d_in[2];
  // d_in[3] = mask: deterministic causal tril, implemented analytically
  const float* Wq = (const float*)d_in[4];
  const float* Wk = (const float*)d_in[5];
  const float* Wv = (const float*)d_in[6];
  const float* Wf = (const float*)d_in[7];

  u16* qT  = (u16*)d_ws;                             // [bh][s][d]   8 MiB
  u16* kT  = qT + (size_t)NB * NH * NS * HDIM;       // [bh][s][d]   8 MiB
  u16* vv  = kT + (size_t)NB * NH * NS * HDIM;       // [bh][d][s]   8 MiB
  u16* vvs = vv + (size_t)NB * NH * HDIM * NS;       // [bh][d][s]   8 MiB (V')
  u16* X   = vvs + (size_t)NB * NH * HDIM * NS;      // [b][s][f]    8 MiB
  u16* Wf16 = X + (size_t)NB * NS * NE;              // [e][f]       2 MiB

  proj_kernel<<<dim3(4, 64, 4), 256, 0, stream>>>(q_in, k_in, v_in, Wq, Wk, Wv,
                                                  Wf, qT, kT, vv, Wf16);
  denom_kernel<<<dim3(512), 256, 0, stream>>>(qT, kT, vv, vvs);
  attn_kernel<<<dim3(512), 256, 0, stream>>>(qT, kT, vvs, X);
  final_gemm<<<dim3(8, 8, 4), 256, 0, stream>>>(Wf16, X, (float*)d_out);
}

// Round 8
// 76.379 us; speedup vs baseline: 1.1379x; 1.1379x over previous
//
#include <hip/hip_runtime.h>
#include <hip/hip_bf16.h>
#include <stdint.h>

// MultiHeadAttention pipeline for MI355X (gfx950), all-MFMA bf16.
// Reference's "softmax" divides e[s,t] by D[t] (row-sum of row t), so the
// denominator is per-KEY: out[d,i] = sum_j e[i,j] * rD[j] * v[d,j].
// Round 8: attn occupancy fix — grid was 512 = 2 blocks/CU (the real cap).
// attn: QBLK=64, KBLK=64, 256thr/4 waves, 27.9KB LDS -> 5 blocks/CU by LDS,
// grid 1024 heavy-first -> 4 blocks/CU. Exact per-wave diagonal decomposition
// (full / masked / zero-fill). denom, proj, final_gemm identical to round 6.
#define NB 4
#define NH 16
#define HDIM 64
#define NS 1024
#define NE 1024

typedef __bf16 bf16x8 __attribute__((ext_vector_type(8)));
typedef __bf16 bf16x2_t __attribute__((ext_vector_type(2)));
typedef float f32x4 __attribute__((ext_vector_type(4)));
typedef unsigned int uint4v __attribute__((ext_vector_type(4)));
typedef unsigned int uint2v __attribute__((ext_vector_type(2)));
typedef unsigned short u16;

#if defined(__has_builtin)
#if __has_builtin(__builtin_amdgcn_global_load_lds)
#define HAVE_GLDS 1
#endif
#endif

__device__ __forceinline__ u16 f2bf(float f) {
  return __builtin_bit_cast(u16, (__bf16)f);   // RNE
}
__device__ __forceinline__ unsigned pk2(float a, float b) {
  bf16x2_t v; v[0] = (__bf16)a; v[1] = (__bf16)b;
  return __builtin_bit_cast(unsigned, v);      // v_cvt_pk_bf16_f32
}
__device__ __forceinline__ float fexp2(float x) {
#if defined(__has_builtin)
#if __has_builtin(__builtin_amdgcn_exp2f)
  return __builtin_amdgcn_exp2f(x);
#else
  return __expf(x * 0.69314718056f);
#endif
#else
  return __expf(x * 0.69314718056f);
#endif
}
__device__ __forceinline__ f32x4 mfma16(bf16x8 a, bf16x8 b, f32x4 c) {
  return __builtin_amdgcn_mfma_f32_16x16x32_bf16(a, b, c, 0, 0, 0);
}
__device__ __forceinline__ bf16x8 ld_bf8(const u16* p) {
  return __builtin_bit_cast(bf16x8, *(const uint4v*)p);
}
#ifdef HAVE_GLDS
__device__ __forceinline__ void gld16(const void* g, void* l) {
  __builtin_amdgcn_global_load_lds(
      (__attribute__((address_space(1))) void*)g,
      (__attribute__((address_space(3))) void*)l, 16, 0, 0);
}
#endif

// ---------------------------------------------------------------------------
// Kernel 1: per-head projections q/k/v (z=0..2) + Wf fp32->bf16 (z=3).
// Wq pre-scaled by log2e/8 (log2-domain scores). qT/kT: [bh][s][d]; v: [bh][d][s].
__global__ __launch_bounds__(256) void proj_kernel(
    const float* __restrict__ q_in, const float* __restrict__ k_in,
    const float* __restrict__ v_in, const float* __restrict__ Wq,
    const float* __restrict__ Wk, const float* __restrict__ Wv,
    const float* __restrict__ Wf,
    u16* __restrict__ qT, u16* __restrict__ kT, u16* __restrict__ vv,
    u16* __restrict__ Wf16)
{
  const int which = blockIdx.z;
  const int tid = threadIdx.x;

  if (which == 3) {  // Wf conversion
    int chunk = blockIdx.y * 4 + blockIdx.x;
    #pragma unroll
    for (int jj = 0; jj < 4; ++jj) {
      int i = chunk * 1024 + tid + 256 * jj;
      float4 f = ((const float4*)Wf)[i];
      uint2v p;
      p[0] = pk2(f.x, f.y);
      p[1] = pk2(f.z, f.w);
      ((uint2v*)Wf16)[i] = p;
    }
    return;
  }

  const int bh = blockIdx.y;
  const int b = bh >> 4, h = bh & 15;
  const int s0 = blockIdx.x * 256;
  const int w = tid >> 6, l = tid & 63, lr = l & 15, lg = l >> 4;

  const float* x = (which == 0) ? q_in : (which == 1) ? k_in : v_in;
  const float* W = ((which == 0) ? Wq : (which == 1) ? Wk : Wv) + h * 4096;
  const float wsc = (which == 0) ? 0.18033688f : 1.0f;  // (1/8)*log2(e)

  __shared__ alignas(16) u16 xT[256][72];
  __shared__ alignas(16) u16 Wl[64][72];

  #pragma unroll
  for (int j = 0; j < 4; ++j) {
    int i = tid * 4 + j;
    int d = i >> 4;
    int e0 = (i & 15) * 4;
    float4 f = *(const float4*)(W + d * 64 + e0);
    uint2v p;
    p[0] = pk2(f.x * wsc, f.y * wsc);
    p[1] = pk2(f.z * wsc, f.w * wsc);
    *(uint2v*)&Wl[d][e0] = p;
  }
  {
    const float* xp = x + ((size_t)b * NE + h * 64) * NS + s0 + tid;
    #pragma unroll
    for (int j = 0; j < 8; ++j) {
      uint4v pk;
      #pragma unroll
      for (int q = 0; q < 4; ++q) {
        float f0 = xp[(size_t)(j * 8 + q * 2) * NS];
        float f1 = xp[(size_t)(j * 8 + q * 2 + 1) * NS];
        pk[q] = pk2(f0, f1);
      }
      *(uint4v*)&xT[tid][j * 8] = pk;
    }
  }
  __syncthreads();

  bf16x8 af[4][2];
  #pragma unroll
  for (int mt = 0; mt < 4; ++mt) {
    af[mt][0] = ld_bf8(&Wl[mt * 16 + lr][lg * 8]);
    af[mt][1] = ld_bf8(&Wl[mt * 16 + lr][32 + lg * 8]);
  }
  f32x4 acc[4][4] = {};
  #pragma unroll
  for (int nt = 0; nt < 4; ++nt) {
    bf16x8 b0 = ld_bf8(&xT[w * 64 + nt * 16 + lr][lg * 8]);
    bf16x8 b1 = ld_bf8(&xT[w * 64 + nt * 16 + lr][32 + lg * 8]);
    #pragma unroll
    for (int mt = 0; mt < 4; ++mt) {
      acc[mt][nt] = mfma16(af[mt][0], b0, acc[mt][nt]);
      acc[mt][nt] = mfma16(af[mt][1], b1, acc[mt][nt]);
    }
  }

  if (which < 2) {
    u16* o = ((which == 0) ? qT : kT) + (size_t)bh * NS * 64;
    #pragma unroll
    for (int mt = 0; mt < 4; ++mt)
      #pragma unroll
      for (int nt = 0; nt < 4; ++nt) {
        int s = s0 + w * 64 + nt * 16 + lr;
        int d = mt * 16 + lg * 4;
        uint2v p;
        p[0] = pk2(acc[mt][nt][0], acc[mt][nt][1]);
        p[1] = pk2(acc[mt][nt][2], acc[mt][nt][3]);
        *(uint2v*)(o + (size_t)s * 64 + d) = p;
      }
  } else {
    u16* o = vv + (size_t)bh * 64 * NS;
    #pragma unroll
    for (int mt = 0; mt < 4; ++mt)
      #pragma unroll
      for (int nt = 0; nt < 4; ++nt)
        #pragma unroll
        for (int jr = 0; jr < 4; ++jr) {
          int d = mt * 16 + lg * 4 + jr;
          int s = s0 + w * 64 + nt * 16 + lr;
          o[(size_t)d * NS + s] = f2bf(acc[mt][nt][jr]);
        }
  }
}

// ---------------------------------------------------------------------------
// Kernel 2: denom. QBLK=128 (8 waves), KBLK=128, swapped QK (A=K m=key,
// B=Q n=query). Scores in log2 domain; full tiles unmasked, diagonal masked.
// Writes l2rD[bh][s] = -log2(D[s]). grid 512, heavy-first.
__global__ __launch_bounds__(512) void denom_kernel(
    const u16* __restrict__ qT, const u16* __restrict__ kT,
    float* __restrict__ l2rDg)
{
  const int wg = blockIdx.x;
  const int rt = 7 - (wg >> 6);
  const int bh = wg & 63;
  const int i0 = rt * 128;
  const int tid = threadIdx.x, w = tid >> 6, l = tid & 63, lr = l & 15, lg = l >> 4;
  __shared__ alignas(16) u16 klds[128][72];   // 144B rows (16B multiple)
  const u16* qb = qT + (size_t)bh * NS * 64;
  const u16* kb = kT + (size_t)bh * NS * 64;
  const int gi = i0 + w * 16 + lr;
  bf16x8 bq0 = ld_bf8(qb + (size_t)gi * 64 + lg * 8);
  bf16x8 bq1 = ld_bf8(qb + (size_t)gi * 64 + 32 + lg * 8);
  float den = 0.f;
  const int nkt = rt + 1;
  uint4v kreg[2];
  const int krow = tid >> 3, kcx = tid & 7;  // chunks c = tid + 512j
  #pragma unroll
  for (int j = 0; j < 2; ++j)
    kreg[j] = *(const uint4v*)(kb + (size_t)(krow + j * 64) * 64 + kcx * 8);
  for (int t = 0; t < nkt; ++t) {
    __syncthreads();
    #pragma unroll
    for (int j = 0; j < 2; ++j)
      *(uint4v*)&klds[krow + j * 64][kcx * 8] = kreg[j];
    __syncthreads();
    const int t0 = t * 128;
    if (t + 1 < nkt) {
      #pragma unroll
      for (int j = 0; j < 2; ++j)
        kreg[j] = *(const uint4v*)(kb + (size_t)(t0 + 128 + krow + j * 64) * 64 + kcx * 8);
    }
    if (t + 1 < nkt) {  // full tiles: no causal mask needed
      #pragma unroll
      for (int mt = 0; mt < 8; ++mt) {
        bf16x8 a0 = ld_bf8(&klds[mt * 16 + lr][lg * 8]);
        bf16x8 a1 = ld_bf8(&klds[mt * 16 + lr][32 + lg * 8]);
        f32x4 z = {0.f, 0.f, 0.f, 0.f};
        f32x4 sc = mfma16(a0, bq0, z);
        sc = mfma16(a1, bq1, sc);
        den += fexp2(sc[0]) + fexp2(sc[1]) + fexp2(sc[2]) + fexp2(sc[3]);
      }
    } else {  // diagonal tile: mask gt > gi
      #pragma unroll
      for (int mt = 0; mt < 8; ++mt) {
        bf16x8 a0 = ld_bf8(&klds[mt * 16 + lr][lg * 8]);
        bf16x8 a1 = ld_bf8(&klds[mt * 16 + lr][32 + lg * 8]);
        f32x4 z = {0.f, 0.f, 0.f, 0.f};
        f32x4 sc = mfma16(a0, bq0, z);
        sc = mfma16(a1, bq1, sc);
        #pragma unroll
        for (int r = 0; r < 4; ++r) {
          int gt = t0 + mt * 16 + lg * 4 + r;
          den += (gt <= gi) ? fexp2(sc[r]) : 0.f;
        }
      }
    }
  }
  den += __shfl_xor(den, 16);
  den += __shfl_xor(den, 32);
  if (l < 16) l2rDg[(size_t)bh * NS + gi] = -__log2f(den);
}

// ---------------------------------------------------------------------------
// Kernel 3: attention. QBLK=64, KBLK=64, 256thr/4 waves (wave = 16 q-rows),
// swapped QK, P = exp2(sc + l2rD[j]). Per-wave diagonal decomposition:
// mt<w full, mt==w masked, mt>w zero-fill (wave-uniform). 27.9KB LDS ->
// 5 blocks/CU; grid 1024 heavy-first -> 4 blocks/CU.
__global__ __launch_bounds__(256) void attn_kernel(
    const u16* __restrict__ qT, const u16* __restrict__ kT,
    const u16* __restrict__ vv, const float* __restrict__ l2rDg,
    u16* __restrict__ X)
{
  const int wg = blockIdx.x;
  const int rt = 15 - (wg >> 6);
  const int bh = wg & 63;
  const int b = bh >> 4, h = bh & 15;
  const int i0 = rt * 64;
  const int tid = threadIdx.x, w = tid >> 6, l = tid & 63, lr = l & 15, lg = l >> 4;
  __shared__ alignas(16) u16 klds[64][72];     // [key][d]
  __shared__ alignas(16) u16 vlds[64][72];     // [d][j]
  __shared__ alignas(16) u16 plds[4][16][72];  // per-wave [q-row][key]
  __shared__ alignas(16) float dlds[64];
  const u16* qb = qT + (size_t)bh * NS * 64;
  const u16* kb = kT + (size_t)bh * NS * 64;
  const u16* vb = vv + (size_t)bh * 64 * NS;
  const float* rb = l2rDg + (size_t)bh * NS;
  const int gi = i0 + w * 16 + lr;
  bf16x8 bq0 = ld_bf8(qb + (size_t)gi * 64 + lg * 8);
  bf16x8 bq1 = ld_bf8(qb + (size_t)gi * 64 + 32 + lg * 8);
  f32x4 acc[4] = {};
  const int nkt = rt + 1;
  uint4v kreg[2], vreg[2];
  float dreg = 0.f;
  const int krow = tid >> 3, kcx = tid & 7;   // rows 0..31 (+32 for j=1)
  #pragma unroll
  for (int j = 0; j < 2; ++j) {
    kreg[j] = *(const uint4v*)(kb + (size_t)(krow + j * 32) * 64 + kcx * 8);
    vreg[j] = *(const uint4v*)(vb + (size_t)(krow + j * 32) * NS + kcx * 8);
  }
  if (tid < 64) dreg = rb[tid];
  for (int t = 0; t < nkt; ++t) {
    __syncthreads();
    #pragma unroll
    for (int j = 0; j < 2; ++j) {
      *(uint4v*)&klds[krow + j * 32][kcx * 8] = kreg[j];
      *(uint4v*)&vlds[krow + j * 32][kcx * 8] = vreg[j];
    }
    if (tid < 64) dlds[tid] = dreg;
    __syncthreads();
    const int t0 = t * 64;
    if (t + 1 < nkt) {
      const int t0n = t0 + 64;
      #pragma unroll
      for (int j = 0; j < 2; ++j) {
        kreg[j] = *(const uint4v*)(kb + (size_t)(t0n + krow + j * 32) * 64 + kcx * 8);
        vreg[j] = *(const uint4v*)(vb + (size_t)(krow + j * 32) * NS + t0n + kcx * 8);
      }
      if (tid < 64) dreg = rb[t0n + tid];
    }
    const bool diag = (t + 1 == nkt);
    // QK^T: A=K (m=key), B=Q (n=query); exp2(sc + l2rd) -> plds
    #pragma unroll
    for (int mt = 0; mt < 4; ++mt) {
      if (diag && mt > w) {  // keys entirely above the diagonal: P = 0
        uint2v zz = {0u, 0u};
        *(uint2v*)&plds[w][lr][mt * 16 + lg * 4] = zz;
        continue;
      }
      bf16x8 a0 = ld_bf8(&klds[mt * 16 + lr][lg * 8]);
      bf16x8 a1 = ld_bf8(&klds[mt * 16 + lr][32 + lg * 8]);
      f32x4 z = {0.f, 0.f, 0.f, 0.f};
      f32x4 sc = mfma16(a0, bq0, z);
      sc = mfma16(a1, bq1, sc);
      f32x4 l2 = *(const f32x4*)&dlds[mt * 16 + lg * 4];
      uint2v p;
      if (diag && mt == w) {  // straddles the diagonal: mask per element
        int g0 = t0 + mt * 16 + lg * 4;
        float e0 = (g0 + 0 <= gi) ? fexp2(sc[0] + l2[0]) : 0.f;
        float e1 = (g0 + 1 <= gi) ? fexp2(sc[1] + l2[1]) : 0.f;
        float e2 = (g0 + 2 <= gi) ? fexp2(sc[2] + l2[2]) : 0.f;
        float e3 = (g0 + 3 <= gi) ? fexp2(sc[3] + l2[3]) : 0.f;
        p[0] = pk2(e0, e1);
        p[1] = pk2(e2, e3);
      } else {               // fully below the diagonal: no mask
        p[0] = pk2(fexp2(sc[0] + l2[0]), fexp2(sc[1] + l2[1]));
        p[1] = pk2(fexp2(sc[2] + l2[2]), fexp2(sc[3] + l2[3]));
      }
      *(uint2v*)&plds[w][lr][mt * 16 + lg * 4] = p;
    }
    // PV: A = P (m=query, k=j), B = v (k=j, n=d)
    bf16x8 ap0 = ld_bf8(&plds[w][lr][lg * 8]);
    bf16x8 ap1 = ld_bf8(&plds[w][lr][32 + lg * 8]);
    __builtin_amdgcn_s_setprio(1);
    #pragma unroll
    for (int nt = 0; nt < 4; ++nt) {
      bf16x8 v0 = ld_bf8(&vlds[nt * 16 + lr][lg * 8]);
      bf16x8 v1 = ld_bf8(&vlds[nt * 16 + lr][32 + lg * 8]);
      acc[nt] = mfma16(ap0, v0, acc[nt]);
      acc[nt] = mfma16(ap1, v1, acc[nt]);
    }
    __builtin_amdgcn_s_setprio(0);
  }
  u16* Xp = X + (size_t)b * NS * NE + h * 64;
  #pragma unroll
  for (int nt = 0; nt < 4; ++nt)
    #pragma unroll
    for (int jr = 0; jr < 4; ++jr) {
      int s = i0 + w * 16 + lg * 4 + jr;
      Xp[(size_t)s * NE + nt * 16 + lr] = f2bf(acc[nt][jr]);
    }
}

// ---------------------------------------------------------------------------
// Kernel 4: out[b][e][s] = sum_f Wf[e][f] * X[b][s][f]. 128x128 tile, 4 waves
// (each 64x64), BK=64, global_load_lds into double-buffered XOR-swizzled LDS.
__global__ __launch_bounds__(256) void final_gemm(
    const u16* __restrict__ Wf16, const u16* __restrict__ X,
    float* __restrict__ out)
{
  const int b = blockIdx.z;
  const int e0 = blockIdx.y * 128;
  const int s0 = blockIdx.x * 128;
  const int tid = threadIdx.x, w = tid >> 6, l = tid & 63, lr = l & 15, lg = l >> 4;
  const int wm = (w >> 1) * 64, wn = (w & 1) * 64;
  __shared__ alignas(16) u16 Ald[2][128][64];
  __shared__ alignas(16) u16 Bld[2][128][64];
  const u16* Xb = X + (size_t)b * NS * NE;
  f32x4 acc[4][4] = {};

  // chunk c = tid + 256j: row = c>>3, byte col (c&7)*16, XOR-swizzled source
  #define FG_ISSUE(p, k0)                                                     \
    {                                                                         \
      _Pragma("unroll")                                                       \
      for (int j = 0; j < 4; ++j) {                                           \
        int c = tid + 256 * j;                                                \
        int r = c >> 3;                                                       \
        int sc_ = ((c & 7) * 16) ^ ((r & 7) << 4);                            \
        const char* ga = (const char*)(Wf16 + (size_t)(e0 + r) * NE + (k0)) + sc_; \
        const char* gb = (const char*)(Xb + (size_t)(s0 + r) * NE + (k0)) + sc_;   \
        char* la = (char*)&Ald[p][0][0] + c * 16;                             \
        char* lb = (char*)&Bld[p][0][0] + c * 16;                             \
        STAGE16(ga, la);                                                      \
        STAGE16(gb, lb);                                                      \
      }                                                                       \
    }
#ifdef HAVE_GLDS
  #define STAGE16(g, l_) gld16((g), (l_))
#else
  #define STAGE16(g, l_) (*(uint4v*)(l_) = *(const uint4v*)(g))
#endif

  FG_ISSUE(0, 0);
  __syncthreads();
  for (int t = 0; t < 16; ++t) {
    const int p = t & 1;
    if (t < 15) FG_ISSUE(p ^ 1, (t + 1) * 64);
    __builtin_amdgcn_s_setprio(1);
    #pragma unroll
    for (int kk = 0; kk < 2; ++kk) {
      bf16x8 a[4], bb[4];
      #pragma unroll
      for (int mt = 0; mt < 4; ++mt) {
        int R = wm + mt * 16 + lr;
        a[mt] = ld_bf8((const u16*)((const char*)&Ald[p][R][0] +
                                    ((kk * 64 + lg * 16) ^ ((R & 7) << 4))));
      }
      #pragma unroll
      for (int nt = 0; nt < 4; ++nt) {
        int R = wn + nt * 16 + lr;
        bb[nt] = ld_bf8((const u16*)((const char*)&Bld[p][R][0] +
                                     ((kk * 64 + lg * 16) ^ ((R & 7) << 4))));
      }
      #pragma unroll
      for (int mt = 0; mt < 4; ++mt)
        #pragma unroll
        for (int nt = 0; nt < 4; ++nt)
          acc[mt][nt] = mfma16(a[mt], bb[nt], acc[mt][nt]);
    }
    __builtin_amdgcn_s_setprio(0);
    __syncthreads();
  }
  #pragma unroll
  for (int mt = 0; mt < 4; ++mt)
    #pragma unroll
    for (int nt = 0; nt < 4; ++nt) {
      int e = e0 + wm + mt * 16 + lg * 4;
      int s = s0 + wn + nt * 16 + lr;
      float* op = out + ((size_t)b * NE + e) * NS + s;
      op[0] = acc[mt][nt][0];
      op[NS] = acc[mt][nt][1];
      op[2 * NS] = acc[mt][nt][2];
      op[3 * NS] = acc[mt][nt][3];
    }
}

// ---------------------------------------------------------------------------
extern "C" void kernel_launch(void* const* d_in, const int* in_sizes, int n_in,
                              void* d_out, int out_size, void* d_ws, size_t ws_size,
                              hipStream_t stream) {
  (void)in_sizes; (void)n_in; (void)out_size; (void)ws_size;
  const float* q_in = (const float*)d_in[0];
  const float* k_in = (const float*)d_in[1];
  const float* v_in = (const float*)d_in[2];
  // d_in[3] = mask: deterministic causal tril, implemented analytically
  const float* Wq = (const float*)d_in[4];
  const float* Wk = (const float*)d_in[5];
  const float* Wv = (const float*)d_in[6];
  const float* Wf = (const float*)d_in[7];

  u16* qT = (u16*)d_ws;                              // [bh][s][d]   8 MiB
  u16* kT = qT + (size_t)NB * NH * NS * HDIM;        // [bh][s][d]   8 MiB
  u16* vv = kT + (size_t)NB * NH * NS * HDIM;        // [bh][d][s]   8 MiB
  u16* X  = vv + (size_t)NB * NH * HDIM * NS;        // [b][s][f]    8 MiB
  u16* Wf16 = X + (size_t)NB * NS * NE;              // [e][f]       2 MiB
  float* l2rD = (float*)(Wf16 + (size_t)NE * NE);    // [bh][s]    256 KiB

  proj_kernel<<<dim3(4, 64, 4), 256, 0, stream>>>(q_in, k_in, v_in, Wq, Wk, Wv,
                                                  Wf, qT, kT, vv, Wf16);
  denom_kernel<<<dim3(512), 512, 0, stream>>>(qT, kT, l2rD);
  attn_kernel<<<dim3(1024), 256, 0, stream>>>(qT, kT, vv, l2rD, X);
  final_gemm<<<dim3(8, 8, 4), 256, 0, stream>>>(Wf16, X, (float*)d_out);
}